// Round 1
// 87.676 us; speedup vs baseline: 1.0368x; 1.0368x over previous
//
#include <hip/hip_runtime.h>
#include <hip/hip_bf16.h>
#include <math.h>

#define B_DIM 8
#define T_DIM 1024
#define D_DIM 512
#define NBLK 256             // 8 batches x 32 tiles of 32 queries

typedef __bf16 bf16x8 __attribute__((ext_vector_type(8)));
typedef float floatx4 __attribute__((ext_vector_type(4)));

__device__ __forceinline__ float wave_reduce_sum(float v) {
#pragma unroll
    for (int off = 32; off > 0; off >>= 1) v += __shfl_xor(v, off, 64);
    return v;
}

// fast stable softplus (validated R10/R12): max(y,0)+log(1+exp(-|y|))
__device__ __forceinline__ float softplus(float y) {
    return fmaxf(y, 0.0f) + __logf(1.0f + __expf(-fabsf(y)));
}

// 8 fp32 -> bf16x8 fragment, RNE (validated rounds 7-13)
__device__ __forceinline__ bf16x8 cvt8(float4 x, float4 y) {
    union { ushort u[8]; bf16x8 v; } r;
    __hip_bfloat162 h0 = __float22bfloat162_rn(make_float2(x.x, x.y));
    __hip_bfloat162 h1 = __float22bfloat162_rn(make_float2(x.z, x.w));
    __hip_bfloat162 h2 = __float22bfloat162_rn(make_float2(y.x, y.y));
    __hip_bfloat162 h3 = __float22bfloat162_rn(make_float2(y.z, y.w));
    ushort2 p0 = *(ushort2*)&h0, p1 = *(ushort2*)&h1;
    ushort2 p2 = *(ushort2*)&h2, p3 = *(ushort2*)&h3;
    r.u[0] = p0.x; r.u[1] = p0.y; r.u[2] = p1.x; r.u[3] = p1.y;
    r.u[4] = p2.x; r.u[5] = p2.y; r.u[6] = p3.x; r.u[7] = p3.y;
    return r.v;
}

// LDS-staged 32-query crossband tile.
//  - 1024 threads (16 waves), 1 block/CU (LDS ~147 KiB), XCD swizzle b = blk&7.
//  - Stage: 64 rows x 512 of m and a -> bf16 LDS, fused row sumsq -> inv norms.
//  - MFMA: waves 0-7 own one 16x16 tile of the cross-band union, full K=512,
//    single accumulator chain (no k-split partials, deterministic).
//  - Tile set (rt,ct) relative to rows/cols t0-16 .. t0+47:
//    (1,0)(1,1)(1,2)(2,1)(2,2)(2,3) for m2a, plus (0,1)(3,2) for a2m.
//  - Epilogue: identical mask math to validated rounds 7/9, i2 in [0,32),
//    col-tile base s2+tj so every query's 32-wide band is fully covered.
__global__ __launch_bounds__(1024, 4) void crossband_kernel(
    const float* __restrict__ m, const float* __restrict__ a,
    const float* __restrict__ pscale, const float* __restrict__ pbias,
    float* __restrict__ part_loss, float* __restrict__ part_corr)
{
    // +8 ushort (16B) row pad: staging writes and fragment reads both land at
    // exactly 8 accesses/bank (floor) -> zero excess LDS conflict.
    __shared__ __align__(16) ushort Abf[64][520];   // m rows, bf16
    __shared__ __align__(16) ushort Bbf[64][520];   // a rows, bf16
    __shared__ float Sbuf[64][65];                  // raw scores (8 tiles used)
    __shared__ float normM[64], normA[64];          // inv norms of staged rows
    __shared__ float rowpos[32], colpos[32], shl[16];

    const int blk = blockIdx.x;
    const int b   = blk & 7;                 // XCD-local batch (speed-only)
    const int t0  = (blk >> 3) << 5;         // 32 queries per block
    const int tid  = threadIdx.x;
    const int w    = tid >> 6;
    const int lane = tid & 63;

    // ---- stage + norms: thread = (row j, 32-float slice p) ----
    {
        const int j = tid >> 4, p = tid & 15;
        const int r = min(max(t0 - 16 + j, 0), T_DIM - 1);  // clamped; masked later
        const float* mr = m + ((size_t)b << 19) + (size_t)r * D_DIM + p * 32;
        const float* ar = a + ((size_t)b << 19) + (size_t)r * D_DIM + p * 32;
        float ssm = 0.f, ssa = 0.f;
#pragma unroll
        for (int c = 0; c < 4; ++c) {
            float4 x = *(const float4*)(mr + c * 8);
            float4 y = *(const float4*)(mr + c * 8 + 4);
            ssm += x.x*x.x + x.y*x.y + x.z*x.z + x.w*x.w
                 + y.x*y.x + y.y*y.y + y.z*y.z + y.w*y.w;
            *(bf16x8*)&Abf[j][p * 32 + c * 8] = cvt8(x, y);
            float4 u = *(const float4*)(ar + c * 8);
            float4 v = *(const float4*)(ar + c * 8 + 4);
            ssa += u.x*u.x + u.y*u.y + u.z*u.z + u.w*u.w
                 + v.x*v.x + v.y*v.y + v.z*v.z + v.w*v.w;
            *(bf16x8*)&Bbf[j][p * 32 + c * 8] = cvt8(u, v);
        }
        // 16 lanes share a row (consecutive lanes) -> in-wave reduce
#pragma unroll
        for (int off = 1; off <= 8; off <<= 1) {
            ssm += __shfl_xor(ssm, off, 64);
            ssa += __shfl_xor(ssa, off, 64);
        }
        if (p == 0) {
            normM[j] = 1.0f / fmaxf(sqrtf(ssm), 1e-12f);
            normA[j] = 1.0f / fmaxf(sqrtf(ssa), 1e-12f);
        }
    }
    __syncthreads();

    // ---- MFMA: waves 0-7, one tile each, full K ----
    if (w < 8) {
        // packed 2-bit tables: rt = 1,1,1,2,2,2,0,3  ct = 0,1,2,1,2,3,1,2
        const int rt = (0xCA95 >> (2 * w)) & 3;
        const int ct = (0x9E64 >> (2 * w)) & 3;
        const int mrow = lane & 15, kgrp = lane >> 4;
        floatx4 acc = (floatx4){0.f, 0.f, 0.f, 0.f};
        const ushort* arow = &Abf[rt * 16 + mrow][kgrp * 8];
        const ushort* brow = &Bbf[ct * 16 + mrow][kgrp * 8];
#pragma unroll
        for (int c = 0; c < 16; ++c) {
            bf16x8 af  = *(const bf16x8*)(arow + c * 32);
            bf16x8 bfr = *(const bf16x8*)(brow + c * 32);
            acc = __builtin_amdgcn_mfma_f32_16x16x32_bf16(af, bfr, acc, 0, 0, 0);
        }
        // C layout: col = lane&15, row = (lane>>4)*4 + q (m89-verified)
#pragma unroll
        for (int q = 0; q < 4; ++q)
            Sbuf[rt * 16 + kgrp * 4 + q][ct * 16 + mrow] = acc[q];
    }
    __syncthreads();

    // ---- epilogues (mask math identical to validated rounds 7/9) ----
    const float scale = expf(pscale[0]);
    const float bias  = pbias[0];
    float loss = 0.0f;

    if (tid < 512) {
        // m2a: query t = t0+i2 (Sbuf row 16+i2), cols v = (s2+tj)*16+cc
        int i2 = tid >> 4, cc = tid & 15;
        int s2 = i2 >> 4;
        float im = normM[16 + i2];
        float mmax = -1e30f, mpos = 0.0f;
#pragma unroll
        for (int tj = 0; tj < 3; ++tj) {
            int v  = (s2 + tj) * 16 + cc;
            int dd = v - i2;                   // c - t + 16
            int c  = t0 - 16 + v;
            if (dd >= 0 && dd < 32 && c >= 0 && c < T_DIM) {
                float sv = Sbuf[16 + i2][v] * normA[v];
                float logit = sv * im * scale + bias;
                bool pos = (dd >= 12) && (dd <= 19);
                loss += softplus(pos ? -logit : logit);
                if (sv > mmax) { mmax = sv; mpos = pos ? 1.0f : 0.0f; }
            }
        }
#pragma unroll
        for (int off = 1; off < 16; off <<= 1) {
            float ov = __shfl_xor(mmax, off, 64);
            float op = __shfl_xor(mpos, off, 64);
            if (ov > mmax) { mmax = ov; mpos = op; }
        }
        if (cc == 0) rowpos[i2] = mpos;
    } else {
        // a2m: query t = t0+i2 (Sbuf col 16+i2), rows u2 = (s2+tj)*16+cc
        int t2 = tid - 512;
        int i2 = t2 >> 4, cc = t2 & 15;
        int s2 = i2 >> 4;
        float ia = normA[16 + i2];
        float amax = -1e30f, apos = 0.0f;
#pragma unroll
        for (int tj = 0; tj < 3; ++tj) {
            int u2 = (s2 + tj) * 16 + cc;
            int ee = u2 - i2;                  // r - t + 16
            int rr = t0 - 16 + u2;
            if (ee >= 0 && ee < 32 && rr >= 0 && rr < T_DIM) {
                float sv = Sbuf[u2][16 + i2] * normM[u2];
                float logit = sv * ia * scale + bias;
                bool pos = (ee >= 12) && (ee <= 19);
                loss += softplus(pos ? -logit : logit);
                if (sv > amax) { amax = sv; apos = pos ? 1.0f : 0.0f; }
            }
        }
#pragma unroll
        for (int off = 1; off < 16; off <<= 1) {
            float ov = __shfl_xor(amax, off, 64);
            float op = __shfl_xor(apos, off, 64);
            if (ov > amax) { amax = ov; apos = op; }
        }
        if (cc == 0) colpos[i2] = apos;
    }

    loss = wave_reduce_sum(loss);
    if (lane == 0) shl[w] = loss;
    __syncthreads();
    if (tid == 0) {
        float L = 0.0f, C = 0.0f;
#pragma unroll
        for (int q = 0; q < 16; ++q) L += shl[q];
#pragma unroll
        for (int q = 0; q < 32; ++q) C += rowpos[q] + colpos[q];
        part_loss[blk] = L;
        part_corr[blk] = C;
    }
}

__global__ __launch_bounds__(256) void finalsum_kernel(
    const float* __restrict__ part_loss, const float* __restrict__ part_corr,
    float* __restrict__ out)
{
    int tid = threadIdx.x;
    float l = part_loss[tid];
    float c = part_corr[tid];
    l = wave_reduce_sum(l);
    c = wave_reduce_sum(c);
    __shared__ float shl[4], shc[4];
    int w = tid >> 6, lane = tid & 63;
    if (lane == 0) { shl[w] = l; shc[w] = c; }
    __syncthreads();
    if (tid == 0) {
        out[0] = (shl[0] + shl[1] + shl[2] + shl[3]) / 16384.0f;
        out[1] = (shc[0] + shc[1] + shc[2] + shc[3]) / 16384.0f;
    }
}

extern "C" void kernel_launch(void* const* d_in, const int* in_sizes, int n_in,
                              void* d_out, int out_size, void* d_ws, size_t ws_size,
                              hipStream_t stream)
{
    const float* m  = (const float*)d_in[0];
    const float* a  = (const float*)d_in[1];
    const float* ps = (const float*)d_in[2];
    const float* pb = (const float*)d_in[3];
    float* out = (float*)d_out;

    float* part_loss = (float*)d_ws;          // 256
    float* part_corr = part_loss + NBLK;      // 256

    crossband_kernel<<<NBLK, 1024, 0, stream>>>(m, a, ps, pb,
                                                part_loss, part_corr);
    finalsum_kernel<<<1, 256, 0, stream>>>(part_loss, part_corr, out);
}